// Round 14
// baseline (109.083 us; speedup 1.0000x reference)
//
#include <hip/hip_runtime.h>

#define EPS 1e-5f
#define MAGIC 0x5CA9F1A6u
#define LOG2E 1.44269504f

// NOTE: amdgcn builtins (cvt_pkrtz, fdot2) use __fp16 vectors, not _Float16.
typedef __fp16 h2v2 __attribute__((ext_vector_type(2)));

// Fast reciprocal: single v_rcp_f32 (~1 ulp) instead of IEEE div sequence.
__device__ __forceinline__ float frcp(float x) { return __builtin_amdgcn_rcpf(x); }
// Bare v_exp_f32 (2^x). __exp2f does not exist as a HIP device fn (R13 CE).
__device__ __forceinline__ float fexp2(float x) {
#if __has_builtin(__builtin_amdgcn_exp2f)
    return __builtin_amdgcn_exp2f(x);
#else
    return exp2f(x);
#endif
}
// uniform broadcast of lane k's value -> SGPR (k compile-time constant)
__device__ __forceinline__ int rdli(int v, int k) {
    return __builtin_amdgcn_readlane(v, k);
}
__device__ __forceinline__ float rdl32(float v, int k) {
    return __int_as_float(__builtin_amdgcn_readlane(__float_as_int(v), 32 + k));
}
// Sum of lane m and lane m+32's values, replicated to both halves (semantics-
// agnostic use of permlane32_swap: sum of both outputs = x[m]+x[m+32]).
__device__ __forceinline__ float xhalf_sum(float x) {
#if __has_builtin(__builtin_amdgcn_permlane32_swap)
    auto r = __builtin_amdgcn_permlane32_swap(__float_as_uint(x),
                                              __float_as_uint(x), false, false);
    return __uint_as_float(r[0]) + __uint_as_float(r[1]);
#else
    return x + __shfl_xor(x, 32);
#endif
}
// 2-way f16 dot with f32 accumulate: v_dot2_f32_f16 (2 MACs / instruction)
__device__ __forceinline__ float fdot2(h2v2 a, h2v2 b, float c) {
#if __has_builtin(__builtin_amdgcn_fdot2)
    return __builtin_amdgcn_fdot2(a, b, c, false);
#else
    return c + (float)a.x * (float)b.x + (float)a.y * (float)b.y;
#endif
}

// ---------------------------------------------------------------------------
// R14 = R13 with the __exp2f -> fexp2 (builtin) fix.
// R13 = R12 (staging-free, -16.5us) + serial-chain cuts:
//  (1) Gx and w_hh-f16 pre-scaled by log2(e): gate exps become bare
//      v_exp_f32 (exp2), no chain mul. tanh(c) folds -2*log2e into its one
//      constant mul.
//  (2) fdot2 chains 2-deep (8 chains/gate) -- shorter dependent chain.
//  (3) head weights/biases preloaded into VGPRs BEFORE the scan so their
//      ~200-cycle L2 latencies overlap the scan instead of following it.
//  (4) per-chunk flag polling.
// ---------------------------------------------------------------------------
__global__ __launch_bounds__(64) void fused_kernel(
    const float* __restrict__ x,
    const float* __restrict__ w00, const float* __restrict__ b00,
    const float* __restrict__ w01, const float* __restrict__ b01,
    const float* __restrict__ ln_g, const float* __restrict__ ln_b,
    const float* __restrict__ w_ih, const float* __restrict__ w_hh,
    const float* __restrict__ b_ih, const float* __restrict__ b_hh,
    const float* __restrict__ bn_g, const float* __restrict__ bn_b,
    const float* __restrict__ w10, const float* __restrict__ b10,
    const float* __restrict__ w11, const float* __restrict__ b11,
    const float* __restrict__ w12, const float* __restrict__ b12,
    float* __restrict__ Gx, unsigned* __restrict__ flags,
    float* __restrict__ out)
{
    __shared__ float scr[128];
    const int j = threadIdx.x;

    if (blockIdx.x < 60) {
        // ------------------- frontend (R12 staging-free body) -------------------
        const int t = blockIdx.x;

        scr[j] = (j < 63) ? x[t * 63 + j] : 0.0f;
        __syncthreads();

        float f0 = 0.0f;
        if (j < 63) {
            const float* wr = w00 + j * 63;
            float acc = b00[j];
            #pragma unroll
            for (int k = 0; k < 63; k++) acc += scr[k] * wr[k];
            f0 = fmaxf(acc, 0.0f);
        }
        __syncthreads();
        scr[j] = f0;
        __syncthreads();

        float acc = b01[j];
        {
            const float* wr = w01 + j * 63;
            #pragma unroll
            for (int k = 0; k < 63; k++) acc += scr[k] * wr[k];
        }
        float f1 = fmaxf(acc, 0.0f);

        float s = f1, sq = f1 * f1;
        #pragma unroll
        for (int off = 32; off > 0; off >>= 1) {
            s  += __shfl_xor(s, off);
            sq += __shfl_xor(sq, off);
        }
        float mu  = s * (1.0f / 64.0f);
        float var = sq * (1.0f / 64.0f) - mu * mu;
        float f   = (f1 - mu) * rsqrtf(var + EPS) * ln_g[j] + ln_b[j];
        __syncthreads();
        scr[64 + j] = f;
        __syncthreads();

        float a0 = b_ih[j] + b_hh[j];
        float a1 = b_ih[j + 64] + b_hh[j + 64];
        const float* wi0 = w_ih + j * 64;
        const float* wi1 = w_ih + (j + 64) * 64;
        #pragma unroll
        for (int k = 0; k < 64; k++) {
            float fk = scr[64 + k];
            a0 += fk * wi0[k];
            a1 += fk * wi1[k];
        }
        // pre-scale by log2(e): gate exps in the scan become bare exp2
        Gx[t * 128 + j]      = a0 * LOG2E;
        Gx[t * 128 + 64 + j] = a1 * LOG2E;

        __threadfence();
        __syncthreads();
        if (j == 0)
            __hip_atomic_store(&flags[t], MAGIC, __ATOMIC_RELEASE,
                               __HIP_MEMORY_SCOPE_AGENT);
        return;
    }

    // --------------------------- scan block (1 wave) ---------------------------
    // Stage w_hh rows j and j+64 as f16 PAIRS, pre-scaled by log2(e).
    h2v2 wAh[16], wBh[16];
    {
        const float4* r0 = (const float4*)(w_hh + j * 32);
        const float4* r1 = (const float4*)(w_hh + (j + 64) * 32);
        #pragma unroll
        for (int q = 0; q < 8; q++) {
            float4 a = r0[q];
            float4 b = r1[q];
            wAh[2 * q + 0] = __builtin_amdgcn_cvt_pkrtz(a.x * LOG2E, a.y * LOG2E);
            wAh[2 * q + 1] = __builtin_amdgcn_cvt_pkrtz(a.z * LOG2E, a.w * LOG2E);
            wBh[2 * q + 0] = __builtin_amdgcn_cvt_pkrtz(b.x * LOG2E, b.y * LOG2E);
            wBh[2 * q + 1] = __builtin_amdgcn_cvt_pkrtz(b.z * LOG2E, b.w * LOG2E);
        }
    }

    // Preload head weights/biases into VGPRs: latencies overlap the scan.
    const int ro = j & 31;
    float w10r[32], w11r[32], w12r[4][32];
    float b10r, b11r, b12r[4];
    {
        const float4* p10 = (const float4*)(w10 + ro * 32);
        const float4* p11 = (const float4*)(w11 + ro * 32);
        #pragma unroll
        for (int q = 0; q < 8; q++) {
            float4 a = p10[q];
            w10r[4*q] = a.x; w10r[4*q+1] = a.y; w10r[4*q+2] = a.z; w10r[4*q+3] = a.w;
            float4 b = p11[q];
            w11r[4*q] = b.x; w11r[4*q+1] = b.y; w11r[4*q+2] = b.z; w11r[4*q+3] = b.w;
        }
        #pragma unroll
        for (int r = 0; r < 4; r++) {
            const float4* p12 = (const float4*)(w12 + (j + 64 * r) * 32);
            #pragma unroll
            for (int q = 0; q < 8; q++) {
                float4 v = p12[q];
                w12r[r][4*q] = v.x; w12r[r][4*q+1] = v.y;
                w12r[r][4*q+2] = v.z; w12r[r][4*q+3] = v.w;
            }
            b12r[r] = b12[j + 64 * r];
        }
        b10r = b10[ro];
        b11r = b11[ro];
    }
    // BN params (broadcast via readlane later -> keep per-lane copies)
    float bngr = bn_g[ro], bnbr = bn_b[ro];

    const bool low = (j < 32);
    float c = 0.0f, hn = 0.0f;
    #pragma unroll 1   // keep outer rolled: 5x ~9KB inner would blow L1I
    for (int c0 = 0; c0 < 5; c0++) {
        // per-chunk poll: lane i<12 watches flags[12*c0+i] (relaxed), one
        // ballot per sweep; single acquire for ordering. Poison re-arms.
        {
            bool done = (j >= 12);
            while (true) {
                if (!done)
                    done = (__hip_atomic_load(&flags[12 * c0 + j],
                                              __ATOMIC_RELAXED,
                                              __HIP_MEMORY_SCOPE_AGENT) == MAGIC);
                if (__ballot(done) == ~0ULL) break;
                __builtin_amdgcn_s_sleep(1);
            }
            (void)__hip_atomic_load(&flags[12 * c0], __ATOMIC_ACQUIRE,
                                    __HIP_MEMORY_SCOPE_AGENT);
        }
        // chunk-top bulk refill DIRECT from global (coalesced)
        float gAr[12], gBr[12];
        #pragma unroll
        for (int i = 0; i < 12; i++) {
            gAr[i] = Gx[(c0 * 12 + i) * 128 + j];
            gBr[i] = Gx[(c0 * 12 + i) * 128 + 64 + j];
        }
        #pragma unroll
        for (int i = 0; i < 12; i++) {
            // pack h pairs: DPP quad_perm [1,0,3,2] + v_cvt_pkrtz
            int   hsw_i = __builtin_amdgcn_update_dpp(
                              0, __float_as_int(hn), 0xB1, 0xF, 0xF, true);
            h2v2  hpk   = __builtin_amdgcn_cvt_pkrtz(hn, __int_as_float(hsw_i));
            int   hpk_i = __builtin_bit_cast(int, hpk);

            // 16 readlanes (even high lanes) -> all 32 h values as f16 pairs
            int hh_i[16];
            #pragma unroll
            for (int k = 0; k < 16; k++) hh_i[k] = rdli(hpk_i, 32 + 2 * k);

            // 8 chains x 2-deep fdot2 per gate (short dependent chain)
            float aA[8], aB[8];
            aA[0] = gAr[i]; aB[0] = gBr[i];
            #pragma unroll
            for (int q = 1; q < 8; q++) { aA[q] = 0.f; aB[q] = 0.f; }
            #pragma unroll
            for (int d = 0; d < 2; d++) {
                #pragma unroll
                for (int q = 0; q < 8; q++) {
                    h2v2 hv = __builtin_bit_cast(h2v2, hh_i[d * 8 + q]);
                    aA[q] = fdot2(hv, wAh[d * 8 + q], aA[q]);
                    aB[q] = fdot2(hv, wBh[d * 8 + q], aB[q]);
                }
            }
            float a0 = ((aA[0]+aA[1]) + (aA[2]+aA[3]))
                     + ((aA[4]+aA[5]) + (aA[6]+aA[7]));  // low: i' ; high: f'
            float a1 = ((aB[0]+aB[1]) + (aB[2]+aB[3]))
                     + ((aB[4]+aB[5]) + (aB[6]+aB[7]));  // low: g' ; high: o'

            // nonlinearities on log2e-scaled gates: bare exp2, no chain mul
            float e1 = fexp2(-a1);
            float sO = frcp(1.0f + e1);                 // high: sigm(o)
            float e2 = e1 * e1;                         // exp(-2*g)
            float t1 = (1.0f - e2) * frcp(1.0f + e2);   // low: tanh(g)
            float s0 = frcp(1.0f + fexp2(-a0));         // low: sigm(i); high: sigm(f)
            float own = s0 * (low ? t1 : c);
            c = xhalf_sum(own);          // sigm(i)tanh(g) + sigm(f)*c
            // hn = sigm(o) * tanh(c); fold -2*log2e into one const mul
            float ec = fexp2(c * (-2.0f * LOG2E));
            hn = sO * ((1.0f - ec) * frcp(1.0f + ec));  // valid on high lanes
        }
    }

    // Head -- all weights already in VGPRs (preloaded before the scan)
    const float rs = rsqrtf(1.0f + EPS);
    float acc = b10r;
    #pragma unroll
    for (int k = 0; k < 32; k++) {
        float hkk = rdl32(hn, k);
        // BN params for column k: broadcast from lane k's per-lane copy
        float gk = __int_as_float(rdli(__float_as_int(bngr), k));
        float bk = __int_as_float(rdli(__float_as_int(bnbr), k));
        float hb = hkk * rs * gk + bk;
        acc += w10r[k] * hb;
    }
    float o1 = fmaxf(acc, 0.0f);

    acc = b11r;
    #pragma unroll
    for (int k = 0; k < 32; k++)
        acc += w11r[k]
             * __int_as_float(__builtin_amdgcn_readlane(__float_as_int(o1), k));
    float o2 = fmaxf(acc, 0.0f);

    float a[4];
    #pragma unroll
    for (int r = 0; r < 4; r++) a[r] = b12r[r];
    #pragma unroll
    for (int k = 0; k < 32; k++) {
        float hv = __int_as_float(__builtin_amdgcn_readlane(__float_as_int(o2), k));
        #pragma unroll
        for (int r = 0; r < 4; r++) a[r] += w12r[r][k] * hv;
    }
    #pragma unroll
    for (int r = 0; r < 4; r++) out[j + 64 * r] = a[r];
}

extern "C" void kernel_launch(void* const* d_in, const int* in_sizes, int n_in,
                              void* d_out, int out_size, void* d_ws, size_t ws_size,
                              hipStream_t stream) {
    const float* x    = (const float*)d_in[0];
    const float* w00  = (const float*)d_in[1];
    const float* b00  = (const float*)d_in[2];
    const float* w01  = (const float*)d_in[3];
    const float* b01  = (const float*)d_in[4];
    const float* ln_g = (const float*)d_in[5];
    const float* ln_b = (const float*)d_in[6];
    const float* w_ih = (const float*)d_in[7];
    const float* w_hh = (const float*)d_in[8];
    const float* b_ih = (const float*)d_in[9];
    const float* b_hh = (const float*)d_in[10];
    const float* bn_g = (const float*)d_in[11];
    const float* bn_b = (const float*)d_in[12];
    const float* w10  = (const float*)d_in[13];
    const float* b10  = (const float*)d_in[14];
    const float* w11  = (const float*)d_in[15];
    const float* b11  = (const float*)d_in[16];
    const float* w12  = (const float*)d_in[17];
    const float* b12  = (const float*)d_in[18];
    float* out = (float*)d_out;
    float*    Gx    = (float*)d_ws;                       // 30,720 B
    unsigned* flags = (unsigned*)((char*)d_ws + 49152);   // 60 flags

    fused_kernel<<<61, 64, 0, stream>>>(x, w00, b00, w01, b01, ln_g, ln_b,
                                        w_ih, w_hh, b_ih, b_hh, bn_g, bn_b,
                                        w10, b10, w11, b11, w12, b12,
                                        Gx, flags, out);
}